// Round 19
// baseline (121.228 us; speedup 1.0000x reference)
//
#include <hip/hip_runtime.h>

#define T_SEQ 50
#define BATCH 8192
#define INPUT 33
#define HID   256
#define BTILE 32
#define NTH   512

typedef __attribute__((ext_vector_type(8))) short short8;
typedef __attribute__((ext_vector_type(4))) short short4v;
typedef __attribute__((ext_vector_type(4))) float float4v;

// bf16 h / x staging, double-buffered (units: shorts). 43 KB total.
#define H_STRIDE 264                       // 256 + 8 pad (2-way aliasing = free)
#define X_STRIDE 72                        // 64 + 8
#define H0 0
#define H1 (BTILE * H_STRIDE)              // 8448
#define X0 (2 * BTILE * H_STRIDE)          // 16896
#define X1 (X0 + BTILE * X_STRIDE)         // 19200
#define LDS_SHORTS (X1 + BTILE * X_STRIDE) // 21504 shorts = 43008 B

__device__ __forceinline__ short f2bf(float v) {   // RNE f32 -> bf16 bits
  unsigned u = __builtin_bit_cast(unsigned, v);
  u = (u + 0x7FFFu + ((u >> 16) & 1u)) >> 16;
  return (short)u;
}
__device__ __forceinline__ float bf2f(short s) {
  return __builtin_bit_cast(float, ((unsigned)(unsigned short)s) << 16);
}

// One step (R14 = 95.1us champion). ONLY change: the 4 output-row stores are
// SPLIT 50/50 between the nt path (L2-bypass/streaming) and the normal path
// (L2 write-back) — probing whether the two drain channels are additive.
#define CSTEP(HR, XR, HW, XW, T)                                              \
  {                                                                           \
    float xp0 = 0.f, xp1 = 0.f, xp2 = 0.f;                                    \
    const bool more = (T) + 1 < T_SEQ;                                        \
    if (more) {                                                               \
      const float* xt1 = xpf + (size_t)((T) + 1) * xstep;                     \
      xp0 = xt1[e0]; xp1 = xt1[e1];                                           \
      if (p2) xp2 = xt1[e2];                                                  \
    }                                                                         \
    float4v acc[2][2];                                                        \
    _Pragma("unroll") for (int m = 0; m < 2; ++m)                             \
      _Pragma("unroll") for (int n = 0; n < 2; ++n)                           \
        _Pragma("unroll") for (int i = 0; i < 4; ++i)                         \
          acc[m][n][i] = hst[m][n][i] + bc[n];                                \
    const short* hb = lds + (HR);                                             \
    const short* xb = lds + (XR);                                             \
    _Pragma("unroll") for (int ks = 0; ks < 8; ++ks) {                        \
      const int k = ks * 32 + kq * 8;                                         \
      short8 a0 = *(const short8*)(hb + colA * H_STRIDE + k);                 \
      short8 a1 = *(const short8*)(hb + (16 + colA) * H_STRIDE + k);          \
      acc[0][0] = __builtin_amdgcn_mfma_f32_16x16x32_bf16(a0, wf[0][ks], acc[0][0], 0, 0, 0); \
      acc[0][1] = __builtin_amdgcn_mfma_f32_16x16x32_bf16(a0, wf[1][ks], acc[0][1], 0, 0, 0); \
      acc[1][0] = __builtin_amdgcn_mfma_f32_16x16x32_bf16(a1, wf[0][ks], acc[1][0], 0, 0, 0); \
      acc[1][1] = __builtin_amdgcn_mfma_f32_16x16x32_bf16(a1, wf[1][ks], acc[1][1], 0, 0, 0); \
    }                                                                         \
    _Pragma("unroll") for (int kb = 0; kb < 2; ++kb) {                        \
      const int k = kb * 32 + kq * 8;                                         \
      short8 a0 = *(const short8*)(xb + colA * X_STRIDE + k);                 \
      short8 a1 = *(const short8*)(xb + (16 + colA) * X_STRIDE + k);          \
      acc[0][0] = __builtin_amdgcn_mfma_f32_16x16x32_bf16(a0, win[0][kb], acc[0][0], 0, 0, 0); \
      acc[0][1] = __builtin_amdgcn_mfma_f32_16x16x32_bf16(a0, win[1][kb], acc[0][1], 0, 0, 0); \
      acc[1][0] = __builtin_amdgcn_mfma_f32_16x16x32_bf16(a1, win[0][kb], acc[1][0], 0, 0, 0); \
      acc[1][1] = __builtin_amdgcn_mfma_f32_16x16x32_bf16(a1, win[1][kb], acc[1][1], 0, 0, 0); \
    }                                                                         \
    _Pragma("unroll") for (int m = 0; m < 2; ++m)                             \
      _Pragma("unroll") for (int n = 0; n < 2; ++n)                           \
        _Pragma("unroll") for (int i = 0; i < 4; ++i) {                       \
          float hn = fmaxf(0.5f * acc[m][n][i], 0.0f);                        \
          hst[m][n][i] = hn;                                                  \
          lds[(HW) + (m * 16 + kq * 4 + i) * H_STRIDE + c0 + n * 16 + colA] = \
              f2bf(hn);                                                       \
        }                                                                     \
    if (more) {                                                               \
      lds[(XW) + r0 * X_STRIDE + c0x] = f2bf(xp0);                            \
      lds[(XW) + r1 * X_STRIDE + c1x] = f2bf(xp1);                            \
      if (p2) lds[(XW) + r2 * X_STRIDE + c2x] = f2bf(xp2);                    \
    }                                                                         \
    __builtin_amdgcn_sched_barrier(0);                                        \
    asm volatile("s_waitcnt lgkmcnt(0)" ::: "memory");                        \
    __builtin_amdgcn_s_barrier();                                             \
    __builtin_amdgcn_sched_barrier(0);                                        \
    _Pragma("unroll") for (int j = 0; j < 4; ++j) {                           \
      short4v hv = *(const short4v*)(lds + (HW) + (4 * wave + j) * H_STRIDE + 4 * lane); \
      float4v ov;                                                             \
      ov[0] = bf2f(hv[0]); ov[1] = bf2f(hv[1]);                               \
      ov[2] = bf2f(hv[2]); ov[3] = bf2f(hv[3]);                               \
      if (j < 2)                                                              \
        __builtin_nontemporal_store(ov, (float4v*)(outg + j * HID));          \
      else                                                                    \
        *(float4v*)(outg + j * HID) = ov;                                     \
    }                                                                         \
    outg += outstep;                                                          \
  }

__global__ __launch_bounds__(NTH, 2)
void ctrnn_kernel(const float* __restrict__ x, const int* __restrict__ sub_id,
                  const float* __restrict__ gates, const float* __restrict__ W_in,
                  const float* __restrict__ b_in, const float* __restrict__ W_h,
                  const float* __restrict__ b_h, float* __restrict__ out)
{
  __shared__ short lds[LDS_SHORTS];
  const int tid  = threadIdx.x;
  const int lane = tid & 63;
  const int wave = tid >> 6;
  const int colA = lane & 15;   // MFMA row/col-within-tile index
  const int kq   = lane >> 4;   // k-quadrant / C-row group
  const int c0   = wave * 32;   // wave's output-column base (8 waves x 32)
  const int brow0 = blockIdx.x * BTILE;

  const int sid = sub_id[0];
  const float* grow = gates + sid * HID;

  // ---- zero h/x staging (h0 = 0; x pad columns stay 0 forever) ----
  {
    int* ldsi = (int*)lds;
    #pragma unroll 4
    for (int i = tid; i < LDS_SHORTS / 2; i += NTH) ldsi[i] = 0;
  }

  // ---- t-invariant operands in REGISTERS ----
  short8 wf[2][8];   // B-fragments of W_h' = diag(g)*W_h  (64 VGPRs)
  short8 win[2][2];  // B-fragments of W_in (zero-padded K=64)
  float  bc[2];
  #pragma unroll
  for (int n = 0; n < 2; ++n) {
    const int col = c0 + n * 16 + colA;
    const float g = grow[col];
    #pragma unroll
    for (int ks = 0; ks < 8; ++ks) {
      const float* wp = W_h + col * HID + ks * 32 + kq * 8;
      float4v w0 = *(const float4v*)wp;
      float4v w1 = *(const float4v*)(wp + 4);
      short8 f;
      f[0] = f2bf(g * w0[0]); f[1] = f2bf(g * w0[1]);
      f[2] = f2bf(g * w0[2]); f[3] = f2bf(g * w0[3]);
      f[4] = f2bf(g * w1[0]); f[5] = f2bf(g * w1[1]);
      f[6] = f2bf(g * w1[2]); f[7] = f2bf(g * w1[3]);
      wf[n][ks] = f;
    }
    #pragma unroll
    for (int kb = 0; kb < 2; ++kb) {
      short8 f;
      #pragma unroll
      for (int j = 0; j < 8; ++j) {
        int kk = kb * 32 + kq * 8 + j;
        f[j] = (kk < INPUT) ? f2bf(W_in[col * INPUT + kk]) : (short)0;
      }
      win[n][kb] = f;
    }
    bc[n] = b_in[col] + g * b_h[col];
  }

  __syncthreads();   // zero-fill complete before x0 staging

  // ---- stage x_0 into buffer 0 ----
  {
    const float* xt = x + (size_t)brow0 * INPUT;
    for (int e = tid; e < BTILE * INPUT; e += NTH) {
      int r = e / INPUT, c = e - r * INPUT;
      lds[X0 + r * X_STRIDE + c] = f2bf(xt[e]);
    }
  }

  // x-prefetch invariants (threads cover elems tid, tid+512, tid+1024 of 1056)
  const int e0 = tid, e1 = tid + NTH, e2 = tid + 2 * NTH;
  const int r0 = e0 / INPUT, c0x = e0 - r0 * INPUT;
  const int r1 = e1 / INPUT, c1x = e1 - r1 * INPUT;
  const int r2 = e2 / INPUT, c2x = e2 - r2 * INPUT;
  const bool p2 = (e2 < BTILE * INPUT);

  // persistent f32 h master at MFMA C-layout
  float4v hst[2][2];
  #pragma unroll
  for (int m = 0; m < 2; ++m)
    #pragma unroll
    for (int n = 0; n < 2; ++n)
      #pragma unroll
      for (int i = 0; i < 4; ++i) hst[m][n][i] = 0.0f;

  // coalesced store base: wave w owns tile rows 4w..4w+3, lane covers 16B
  float* outg = out + (size_t)(brow0 + 4 * wave) * HID + 4 * lane;
  const int outstep = BATCH * HID;
  const float* xpf = x + (size_t)brow0 * INPUT;
  const int xstep = BATCH * INPUT;

  __syncthreads();   // x0 staged; h0 zeroed

  #pragma unroll 1
  for (int t2 = 0; t2 < T_SEQ / 2; ++t2) {
    CSTEP(H0, X0, H1, X1, 2 * t2);       // even: read buf0, write buf1
    CSTEP(H1, X1, H0, X0, 2 * t2 + 1);   // odd:  read buf1, write buf0
  }

  // h_last == output[T-1]; read back from H0 (written by step T-1)
  {
    float* hl = out + (size_t)T_SEQ * BATCH * HID +
                (size_t)(brow0 + 4 * wave) * HID + 4 * lane;
    #pragma unroll
    for (int j = 0; j < 4; ++j) {
      short4v hv = *(const short4v*)(lds + H0 + (4 * wave + j) * H_STRIDE + 4 * lane);
      float4v ov;
      ov[0] = bf2f(hv[0]); ov[1] = bf2f(hv[1]);
      ov[2] = bf2f(hv[2]); ov[3] = bf2f(hv[3]);
      if (j < 2)
        __builtin_nontemporal_store(ov, (float4v*)(hl + j * HID));
      else
        *(float4v*)(hl + j * HID) = ov;
    }
  }
}

extern "C" void kernel_launch(void* const* d_in, const int* in_sizes, int n_in,
                              void* d_out, int out_size, void* d_ws, size_t ws_size,
                              hipStream_t stream) {
  const float* x    = (const float*)d_in[0];
  const int*   sid  = (const int*)  d_in[1];
  const float* gts  = (const float*)d_in[2];
  const float* W_in = (const float*)d_in[3];
  const float* b_in = (const float*)d_in[4];
  const float* W_h  = (const float*)d_in[5];
  const float* b_h  = (const float*)d_in[6];
  float* out = (float*)d_out;

  ctrnn_kernel<<<BATCH / BTILE, NTH, 0, stream>>>(x, sid, gts, W_in, b_in, W_h, b_h, out);
}

// Round 20
// 91.302 us; speedup vs baseline: 1.3278x; 1.3278x over previous
//
#include <hip/hip_runtime.h>

#define T_SEQ 50
#define BATCH 8192
#define INPUT 33
#define HID   256
#define BTILE 32
#define NTH   512

typedef __attribute__((ext_vector_type(8))) short short8;
typedef __attribute__((ext_vector_type(4))) short short4v;
typedef __attribute__((ext_vector_type(4))) float float4v;

// bf16 h / x staging, double-buffered (units: shorts). 43 KB total.
#define H_STRIDE 264                       // 256 + 8 pad (2-way aliasing = free)
#define X_STRIDE 72                        // 64 + 8
#define H0 0
#define H1 (BTILE * H_STRIDE)              // 8448
#define X0 (2 * BTILE * H_STRIDE)          // 16896
#define X1 (X0 + BTILE * X_STRIDE)         // 19200
#define LDS_SHORTS (X1 + BTILE * X_STRIDE) // 21504 shorts = 43008 B

__device__ __forceinline__ short f2bf(float v) {   // RNE f32 -> bf16 bits
  unsigned u = __builtin_bit_cast(unsigned, v);
  u = (u + 0x7FFFu + ((u >> 16) & 1u)) >> 16;
  return (short)u;
}
__device__ __forceinline__ float bf2f(short s) {
  return __builtin_bit_cast(float, ((unsigned)(unsigned short)s) << 16);
}

// One step (R14 = 95.1us champion). ONLY change: 2-DEEP x prefetch pipeline.
// Step t issues loads for x(t+2) into LSET and ds_writes x(t+1) from WSET
// (loaded one full step earlier). The vmcnt wait before that ds_write now has
// 7 newer VMEM ops (4 stores + 3 loads) => compiler emits vmcnt(7)-class
// waits that DON'T drain the previous step's output stores. Stores retire in
// background across >=2 steps + the hw queue instead of inside each step.
#define CSTEP(HR, XR, HW, XW, WSET, LSET, T)                                  \
  {                                                                           \
    if ((T) + 2 < T_SEQ) {                                                    \
      const float* xt2 = xpf + (size_t)((T) + 2) * xstep;                     \
      LSET##0 = xt2[e0]; LSET##1 = xt2[e1];                                   \
      if (p2) LSET##2 = xt2[e2];                                              \
    }                                                                         \
    float4v acc[2][2];                                                        \
    _Pragma("unroll") for (int m = 0; m < 2; ++m)                             \
      _Pragma("unroll") for (int n = 0; n < 2; ++n)                           \
        _Pragma("unroll") for (int i = 0; i < 4; ++i)                         \
          acc[m][n][i] = hst[m][n][i] + bc[n];                                \
    const short* hb = lds + (HR);                                             \
    const short* xb = lds + (XR);                                             \
    _Pragma("unroll") for (int ks = 0; ks < 8; ++ks) {                        \
      const int k = ks * 32 + kq * 8;                                         \
      short8 a0 = *(const short8*)(hb + colA * H_STRIDE + k);                 \
      short8 a1 = *(const short8*)(hb + (16 + colA) * H_STRIDE + k);          \
      acc[0][0] = __builtin_amdgcn_mfma_f32_16x16x32_bf16(a0, wf[0][ks], acc[0][0], 0, 0, 0); \
      acc[0][1] = __builtin_amdgcn_mfma_f32_16x16x32_bf16(a0, wf[1][ks], acc[0][1], 0, 0, 0); \
      acc[1][0] = __builtin_amdgcn_mfma_f32_16x16x32_bf16(a1, wf[0][ks], acc[1][0], 0, 0, 0); \
      acc[1][1] = __builtin_amdgcn_mfma_f32_16x16x32_bf16(a1, wf[1][ks], acc[1][1], 0, 0, 0); \
    }                                                                         \
    _Pragma("unroll") for (int kb = 0; kb < 2; ++kb) {                        \
      const int k = kb * 32 + kq * 8;                                         \
      short8 a0 = *(const short8*)(xb + colA * X_STRIDE + k);                 \
      short8 a1 = *(const short8*)(xb + (16 + colA) * X_STRIDE + k);          \
      acc[0][0] = __builtin_amdgcn_mfma_f32_16x16x32_bf16(a0, win[0][kb], acc[0][0], 0, 0, 0); \
      acc[0][1] = __builtin_amdgcn_mfma_f32_16x16x32_bf16(a0, win[1][kb], acc[0][1], 0, 0, 0); \
      acc[1][0] = __builtin_amdgcn_mfma_f32_16x16x32_bf16(a1, win[0][kb], acc[1][0], 0, 0, 0); \
      acc[1][1] = __builtin_amdgcn_mfma_f32_16x16x32_bf16(a1, win[1][kb], acc[1][1], 0, 0, 0); \
    }                                                                         \
    _Pragma("unroll") for (int m = 0; m < 2; ++m)                             \
      _Pragma("unroll") for (int n = 0; n < 2; ++n)                           \
        _Pragma("unroll") for (int i = 0; i < 4; ++i) {                       \
          float hn = fmaxf(0.5f * acc[m][n][i], 0.0f);                        \
          hst[m][n][i] = hn;                                                  \
          lds[(HW) + (m * 16 + kq * 4 + i) * H_STRIDE + c0 + n * 16 + colA] = \
              f2bf(hn);                                                       \
        }                                                                     \
    if ((T) + 1 < T_SEQ) {                                                    \
      lds[(XW) + r0 * X_STRIDE + c0x] = f2bf(WSET##0);                        \
      lds[(XW) + r1 * X_STRIDE + c1x] = f2bf(WSET##1);                        \
      if (p2) lds[(XW) + r2 * X_STRIDE + c2x] = f2bf(WSET##2);                \
    }                                                                         \
    __builtin_amdgcn_sched_barrier(0);                                        \
    asm volatile("s_waitcnt lgkmcnt(0)" ::: "memory");                        \
    __builtin_amdgcn_s_barrier();                                             \
    __builtin_amdgcn_sched_barrier(0);                                        \
    _Pragma("unroll") for (int j = 0; j < 4; ++j) {                           \
      short4v hv = *(const short4v*)(lds + (HW) + (4 * wave + j) * H_STRIDE + 4 * lane); \
      float4v ov;                                                             \
      ov[0] = bf2f(hv[0]); ov[1] = bf2f(hv[1]);                               \
      ov[2] = bf2f(hv[2]); ov[3] = bf2f(hv[3]);                               \
      __builtin_nontemporal_store(ov, (float4v*)(outg + j * HID));            \
    }                                                                         \
    outg += outstep;                                                          \
  }

__global__ __launch_bounds__(NTH, 2)
void ctrnn_kernel(const float* __restrict__ x, const int* __restrict__ sub_id,
                  const float* __restrict__ gates, const float* __restrict__ W_in,
                  const float* __restrict__ b_in, const float* __restrict__ W_h,
                  const float* __restrict__ b_h, float* __restrict__ out)
{
  __shared__ short lds[LDS_SHORTS];
  const int tid  = threadIdx.x;
  const int lane = tid & 63;
  const int wave = tid >> 6;
  const int colA = lane & 15;   // MFMA row/col-within-tile index
  const int kq   = lane >> 4;   // k-quadrant / C-row group
  const int c0   = wave * 32;   // wave's output-column base (8 waves x 32)
  const int brow0 = blockIdx.x * BTILE;

  const int sid = sub_id[0];
  const float* grow = gates + sid * HID;

  // ---- zero h/x staging (h0 = 0; x pad columns stay 0 forever) ----
  {
    int* ldsi = (int*)lds;
    #pragma unroll 4
    for (int i = tid; i < LDS_SHORTS / 2; i += NTH) ldsi[i] = 0;
  }

  // ---- t-invariant operands in REGISTERS ----
  short8 wf[2][8];   // B-fragments of W_h' = diag(g)*W_h  (64 VGPRs)
  short8 win[2][2];  // B-fragments of W_in (zero-padded K=64)
  float  bc[2];
  #pragma unroll
  for (int n = 0; n < 2; ++n) {
    const int col = c0 + n * 16 + colA;
    const float g = grow[col];
    #pragma unroll
    for (int ks = 0; ks < 8; ++ks) {
      const float* wp = W_h + col * HID + ks * 32 + kq * 8;
      float4v w0 = *(const float4v*)wp;
      float4v w1 = *(const float4v*)(wp + 4);
      short8 f;
      f[0] = f2bf(g * w0[0]); f[1] = f2bf(g * w0[1]);
      f[2] = f2bf(g * w0[2]); f[3] = f2bf(g * w0[3]);
      f[4] = f2bf(g * w1[0]); f[5] = f2bf(g * w1[1]);
      f[6] = f2bf(g * w1[2]); f[7] = f2bf(g * w1[3]);
      wf[n][ks] = f;
    }
    #pragma unroll
    for (int kb = 0; kb < 2; ++kb) {
      short8 f;
      #pragma unroll
      for (int j = 0; j < 8; ++j) {
        int kk = kb * 32 + kq * 8 + j;
        f[j] = (kk < INPUT) ? f2bf(W_in[col * INPUT + kk]) : (short)0;
      }
      win[n][kb] = f;
    }
    bc[n] = b_in[col] + g * b_h[col];
  }

  __syncthreads();   // zero-fill complete before x0 staging

  // ---- stage x_0 into buffer 0 ----
  {
    const float* xt = x + (size_t)brow0 * INPUT;
    for (int e = tid; e < BTILE * INPUT; e += NTH) {
      int r = e / INPUT, c = e - r * INPUT;
      lds[X0 + r * X_STRIDE + c] = f2bf(xt[e]);
    }
  }

  // x-prefetch invariants (threads cover elems tid, tid+512, tid+1024 of 1056)
  const int e0 = tid, e1 = tid + NTH, e2 = tid + 2 * NTH;
  const int r0 = e0 / INPUT, c0x = e0 - r0 * INPUT;
  const int r1 = e1 / INPUT, c1x = e1 - r1 * INPUT;
  const int r2 = e2 / INPUT, c2x = e2 - r2 * INPUT;
  const bool p2 = (e2 < BTILE * INPUT);

  const float* xpf = x + (size_t)brow0 * INPUT;
  const int xstep = BATCH * INPUT;

  // 2-deep x pipeline register sets (xA = x(1) initially)
  float xA0 = 0.f, xA1 = 0.f, xA2 = 0.f;
  float xB0 = 0.f, xB1 = 0.f, xB2 = 0.f;
  {
    const float* xt1 = xpf + (size_t)1 * xstep;
    xA0 = xt1[e0]; xA1 = xt1[e1];
    if (p2) xA2 = xt1[e2];
  }

  // persistent f32 h master at MFMA C-layout
  float4v hst[2][2];
  #pragma unroll
  for (int m = 0; m < 2; ++m)
    #pragma unroll
    for (int n = 0; n < 2; ++n)
      #pragma unroll
      for (int i = 0; i < 4; ++i) hst[m][n][i] = 0.0f;

  // coalesced store base: wave w owns tile rows 4w..4w+3, lane covers 16B
  float* outg = out + (size_t)(brow0 + 4 * wave) * HID + 4 * lane;
  const int outstep = BATCH * HID;

  __syncthreads();   // x0 staged; h0 zeroed

  #pragma unroll 1
  for (int t2 = 0; t2 < T_SEQ / 2; ++t2) {
    CSTEP(H0, X0, H1, X1, xA, xB, 2 * t2);       // write x(t+1) from A, load x(t+2) into B
    CSTEP(H1, X1, H0, X0, xB, xA, 2 * t2 + 1);   // write from B, load into A
  }

  // h_last == output[T-1]; read back from H0 (written by step T-1)
  {
    float* hl = out + (size_t)T_SEQ * BATCH * HID +
                (size_t)(brow0 + 4 * wave) * HID + 4 * lane;
    #pragma unroll
    for (int j = 0; j < 4; ++j) {
      short4v hv = *(const short4v*)(lds + H0 + (4 * wave + j) * H_STRIDE + 4 * lane);
      float4v ov;
      ov[0] = bf2f(hv[0]); ov[1] = bf2f(hv[1]);
      ov[2] = bf2f(hv[2]); ov[3] = bf2f(hv[3]);
      __builtin_nontemporal_store(ov, (float4v*)(hl + j * HID));
    }
  }
}

extern "C" void kernel_launch(void* const* d_in, const int* in_sizes, int n_in,
                              void* d_out, int out_size, void* d_ws, size_t ws_size,
                              hipStream_t stream) {
  const float* x    = (const float*)d_in[0];
  const int*   sid  = (const int*)  d_in[1];
  const float* gts  = (const float*)d_in[2];
  const float* W_in = (const float*)d_in[3];
  const float* b_in = (const float*)d_in[4];
  const float* W_h  = (const float*)d_in[5];
  const float* b_h  = (const float*)d_in[6];
  float* out = (float*)d_out;

  ctrnn_kernel<<<BATCH / BTILE, NTH, 0, stream>>>(x, sid, gts, W_in, b_in, W_h, b_h, out);
}